// Round 7
// baseline (342.087 us; speedup 1.0000x reference)
//
#include <hip/hip_runtime.h>
#include <hip/hip_bf16.h>

typedef unsigned short u16;
typedef unsigned int u32;
typedef short short8 __attribute__((ext_vector_type(8)));
typedef float float4v __attribute__((ext_vector_type(4)));
typedef u32 u32x2 __attribute__((ext_vector_type(2)));

#define SEQ 2048
#define DIM 1024
#define NHEAD 16
#define MROWS 4096                       // B*S
#define NE ((size_t)MROWS * DIM)         // 4M elements
#define WN ((size_t)DIM * DIM)           // 1M elements

#if __has_builtin(__builtin_amdgcn_exp2f)
#define EXP2(x) __builtin_amdgcn_exp2f(x)
#else
#define EXP2(x) exp2f(x)
#endif

__device__ inline u16 f2bf(float f) {
    union { float f; unsigned u; } v; v.f = f;
    unsigned r = v.u + 0x7fffu + ((v.u >> 16) & 1u);   // RNE
    return (u16)(r >> 16);
}
__device__ inline float bf2f(u16 s) {
    union { unsigned u; float f; } v; v.u = ((unsigned)s) << 16;
    return v.f;
}
__device__ inline u32 pk2bf(float a, float b) {       // packed RNE bf16x2
    union { __hip_bfloat162 h; u32 u; } cv;
    cv.h = __float22bfloat162_rn(float2{a, b});
    return cv.u;
}
// async global->LDS, 16B per lane; LDS dest = wave-uniform base + lane*16
__device__ inline void gld16(const void* g, void* l) {
    __builtin_amdgcn_global_load_lds(
        (const __attribute__((address_space(1))) void*)g,
        (__attribute__((address_space(3))) void*)l, 16, 0, 0);
}

// ---------------------------------------------------------------------------
// Prep (fused): blocks 0..6143 convert q,k,v fp32->bf16; blocks 6144..7167
// transpose W fp32[k][n] -> bf16 Wt[n][k] (z: 0=w_o,1=w_q,2=w_k,3=w_v).
// ---------------------------------------------------------------------------
__global__ __launch_bounds__(256) void prep(
    const float* __restrict__ q, const float* __restrict__ k,
    const float* __restrict__ v, const float* __restrict__ w_q,
    const float* __restrict__ w_k, const float* __restrict__ w_v,
    const float* __restrict__ w_o, u16* __restrict__ Abf, u16* __restrict__ Wt)
{
    __shared__ u16 T[64 * 66];
    const int bx = blockIdx.x;
    const int tid = threadIdx.x;

    if (bx < 6144) {
        const int z = bx >> 11, xb = bx & 2047;
        const float* s = (z == 0) ? q : (z == 1) ? k : v;
        const size_t i = ((size_t)xb * 256 + tid) * 8;
        float4v a = *(const float4v*)(s + i);
        float4v b = *(const float4v*)(s + i + 4);
        short8 o;
        for (int e = 0; e < 4; e++) { o[e] = (short)f2bf(a[e]); o[4 + e] = (short)f2bf(b[e]); }
        *(short8*)(Abf + (size_t)z * NE + i) = o;
        return;
    }

    const int t = bx - 6144;
    const int z = t & 3, tile = t >> 2;
    const float* src = (z == 0) ? w_o : (z == 1) ? w_q : (z == 2) ? w_k : w_v;
    const int kt = (tile >> 4) * 64, nt = (tile & 15) * 64;
    {
        const int row = tid >> 2, cg = (tid & 3) * 16;
        const float* sp = src + (size_t)(kt + row) * DIM + nt + cg;
        for (int i4 = 0; i4 < 4; i4++) {
            float4v f = *(const float4v*)(sp + i4 * 4);
            for (int e = 0; e < 4; e++)
                T[row * 66 + cg + i4 * 4 + e] = f2bf(f[e]);
        }
    }
    __syncthreads();
    {
        const int nr = tid >> 2, kg = (tid & 3) * 16;
        u16* dp = Wt + (size_t)z * WN + (size_t)(nt + nr) * DIM + kt + kg;
        short8 o0, o1;
        for (int e = 0; e < 8; e++) {
            o0[e] = (short)T[(kg + e) * 66 + nr];
            o1[e] = (short)T[(kg + 8 + e) * 66 + nr];
        }
        *(short8*)(dp) = o0;
        *(short8*)(dp + 8) = o1;
    }
}

// ---------------------------------------------------------------------------
// GEMM qkv: C = A[4096,1024] @ Wt[N,K]^T, 128x128 tile, BK=64, grid (32,8,3).
// z==0 (Q) scales output by 0.125*log2e (folded attention scale).
// z==2 (V) writes output transposed to [bh][d][s] via LDS.
// ---------------------------------------------------------------------------
__global__ __launch_bounds__(256) void gemm_qkv(
    const u16* __restrict__ Abf, const u16* __restrict__ Wtg, u16* __restrict__ QKVb)
{
    __shared__ u16 SMEM[2 * 128 * 64];   // 32 KB: Alds | Wlds ; epilogue-T alias
    u16* Alds = SMEM;
    u16* Wlds = SMEM + 128 * 64;

    const int z = blockIdx.z;
    const u16* A = Abf + (size_t)z * NE;
    const u16* W = Wtg + (size_t)(z + 1) * WN;

    const int tid = threadIdx.x;
    const int lane = tid & 63, w = tid >> 6;
    const int quad = lane >> 4, l16 = lane & 15;
    const int wr = w >> 1, wc = w & 1;
    const int m0 = blockIdx.x * 128, n0 = blockIdx.y * 128;

    float4v acc[4][4];
    float4v vz = {0.f, 0.f, 0.f, 0.f};
    for (int i = 0; i < 4; i++)
        for (int j = 0; j < 4; j++) acc[i][j] = vz;

    for (int k0 = 0; k0 < DIM; k0 += 64) {
        for (int i = 0; i < 4; i++) {
            const int c = tid + i * 256;                   // 1024 chunks each
            const int row = c >> 3, scc = (c & 7) ^ (row & 7);
            gld16(A + (size_t)(m0 + row) * DIM + k0 + scc * 8, &Alds[c * 8]);
            gld16(W + (size_t)(n0 + row) * DIM + k0 + scc * 8, &Wlds[c * 8]);
        }
        __syncthreads();

        for (int s = 0; s < 2; s++) {
            short8 a[4], b[4];
            for (int i = 0; i < 4; i++) {
                const int row = wr * 64 + i * 16 + l16;
                a[i] = *(const short8*)&Alds[row * 64 + (((s * 4 + quad) ^ (row & 7)) * 8)];
            }
            for (int j = 0; j < 4; j++) {
                const int row = wc * 64 + j * 16 + l16;
                b[j] = *(const short8*)&Wlds[row * 64 + (((s * 4 + quad) ^ (row & 7)) * 8)];
            }
            for (int i = 0; i < 4; i++)
                for (int j = 0; j < 4; j++)
                    acc[i][j] = __builtin_amdgcn_mfma_f32_16x16x32_bf16(a[i], b[j], acc[i][j], 0, 0, 0);
        }
        __syncthreads();
    }

    if (z < 2) {                          // Q (pre-scaled), K: natural layout
        const float sc = (z == 0) ? 0.125f * 1.44269504088896f : 1.0f;
        for (int i = 0; i < 4; i++) {
            int row = m0 + wr * 64 + i * 16 + quad * 4;
            for (int j = 0; j < 4; j++) {
                int col = n0 + wc * 64 + j * 16 + l16;
                for (int r = 0; r < 4; r++)
                    QKVb[(size_t)z * NE + (size_t)(row + r) * DIM + col] = f2bf(acc[i][j][r] * sc);
            }
        }
        return;
    }

    // z==2: V -> [bh][d][s] via LDS transpose (chunk-swizzled rows of 128 s)
    u16* T = SMEM;                        // [128 d][128 s], 32 KB
    for (int i = 0; i < 4; i++)
        for (int j = 0; j < 4; j++) {
            const int d = wc * 64 + j * 16 + l16;
            for (int r = 0; r < 4; r++) {
                const int s = wr * 64 + i * 16 + quad * 4 + r;
                T[d * 128 + (((s >> 3) ^ (d & 7)) * 8) + (s & 7)] = f2bf(acc[i][j][r]);
            }
        }
    __syncthreads();
    {
        u16* Vt = QKVb + 2 * NE;
        const int b = m0 >> 11, s_loc = m0 & 2047, h0 = n0 >> 6;
        const int c = lane & 15;                      // s-chunk
        for (int p = 0; p < 8; p++) {
            const int d = w * 32 + (lane >> 4) * 8 + p;
            short8 val = *(const short8*)&T[d * 128 + ((c ^ (d & 7)) * 8)];
            u16* dp = Vt + ((size_t)(b * 16 + h0 + (d >> 6)) * 64 + (d & 63)) * SEQ + s_loc + c * 8;
            *(short8*)dp = val;
        }
    }
}

// ---------------------------------------------------------------------------
// GEMM out: out[4096,1024] fp32 = Cb @ Wt[w_o]^T. 64x128 tile, BK=64,
// grid (64, 8) = 512 blocks (2/CU). Wave tile 32x64 (2x4 frags).
// ---------------------------------------------------------------------------
__global__ __launch_bounds__(256) void gemm_out(
    const u16* __restrict__ Cb, const u16* __restrict__ Wtg, float* __restrict__ out)
{
    __shared__ u16 Alds[64 * 64];        // 8 KB
    __shared__ u16 Wlds[128 * 64];       // 16 KB
    const u16* W = Wtg;                  // w_o at z=0

    const int tid = threadIdx.x;
    const int lane = tid & 63, w = tid >> 6;
    const int quad = lane >> 4, l16 = lane & 15;
    const int wr = w >> 1, wc = w & 1;
    const int m0 = blockIdx.x * 64, n0 = blockIdx.y * 128;

    float4v acc[2][4];
    float4v vz = {0.f, 0.f, 0.f, 0.f};
    for (int i = 0; i < 2; i++)
        for (int j = 0; j < 4; j++) acc[i][j] = vz;

    for (int k0 = 0; k0 < DIM; k0 += 64) {
        for (int i = 0; i < 2; i++) {
            const int c = tid + i * 256;
            const int row = c >> 3, scc = (c & 7) ^ (row & 7);
            gld16(Cb + (size_t)(m0 + row) * DIM + k0 + scc * 8, &Alds[c * 8]);
        }
        for (int i = 0; i < 4; i++) {
            const int c = tid + i * 256;
            const int row = c >> 3, scc = (c & 7) ^ (row & 7);
            gld16(W + (size_t)(n0 + row) * DIM + k0 + scc * 8, &Wlds[c * 8]);
        }
        __syncthreads();

        for (int s = 0; s < 2; s++) {
            short8 a[2], b[4];
            for (int i = 0; i < 2; i++) {
                const int row = wr * 32 + i * 16 + l16;
                a[i] = *(const short8*)&Alds[row * 64 + (((s * 4 + quad) ^ (row & 7)) * 8)];
            }
            for (int j = 0; j < 4; j++) {
                const int row = wc * 64 + j * 16 + l16;
                b[j] = *(const short8*)&Wlds[row * 64 + (((s * 4 + quad) ^ (row & 7)) * 8)];
            }
            for (int i = 0; i < 2; i++)
                for (int j = 0; j < 4; j++)
                    acc[i][j] = __builtin_amdgcn_mfma_f32_16x16x32_bf16(a[i], b[j], acc[i][j], 0, 0, 0);
        }
        __syncthreads();
    }

    for (int i = 0; i < 2; i++) {
        int row = m0 + wr * 32 + i * 16 + quad * 4;
        for (int j = 0; j < 4; j++) {
            int col = n0 + wc * 64 + j * 16 + l16;
            for (int r = 0; r < 4; r++)
                out[(size_t)(row + r) * DIM + col] = acc[i][j][r];
        }
    }
}

// ---------------------------------------------------------------------------
// Attention v4: split-k PV with P aliased into the wave's own dead Klds slice.
// LDS = K 16K + V 16K + L 1K = 33 KB -> 4 blocks/CU (grid 1024 = 4/CU).
// Wave w reads ONLY K-rows w*32..+31 (into registers), then overwrites that
// 4 KB slice with its P[64q][32k] tile -- disjoint regions, no extra barrier.
// Q arrives pre-scaled by 0.125*log2e (folded into gemm_qkv z==0).
// Grid (32 bh, 32 qt) x 256.
// ---------------------------------------------------------------------------
__global__ __launch_bounds__(256, 4) void attn_kernel(
    const u16* __restrict__ Q, const u16* __restrict__ K,
    const u16* __restrict__ Vtg, u16* __restrict__ O)
{
    __shared__ u16 Klds[128 * 64];       // 16KB [k][d] swizzled; per-wave P alias
    __shared__ u16 Vt[64 * 128];         // 16KB [d][k] swizzled
    __shared__ float Llds[4][64];        // 1KB
    float* bufA = (float*)Klds;          // epilogue reduction aliases
    float* bufB = (float*)Vt;

    const int bh = blockIdx.x;
    const int q0 = blockIdx.y * 64;
    const int tid = threadIdx.x;
    const int lane = tid & 63, w = tid >> 6;
    const int quad = lane >> 4, l16 = lane & 15;

    const size_t base = (size_t)(bh >> 4) * SEQ * DIM + (bh & 15) * 64;
    const u16* Qp = Q + base;
    const u16* Kp = K + base;
    u16* Op = O + base;
    const u16* Vp = Vtg + (size_t)bh * 64 * SEQ;   // [d][s]

    // Q B-frags (pre-scaled in gemm_qkv): straight b128 loads
    short8 qb[4][2];
    for (int qc = 0; qc < 4; qc++)
        for (int s = 0; s < 2; s++)
            qb[qc][s] = *(const short8*)(Qp + (size_t)(q0 + qc * 16 + l16) * DIM + s * 32 + quad * 8);

    float4v acc[4][4];
    float4v vz = {0.f, 0.f, 0.f, 0.f};
    for (int qc = 0; qc < 4; qc++)
        for (int nb = 0; nb < 4; nb++) acc[qc][nb] = vz;
    float lp[4] = {0.f, 0.f, 0.f, 0.f};

    u16* pw = Klds + w * 32 * 64;        // wave's 4 KB slice: K rows, then P

    for (int kt = 0; kt < SEQ / 128; kt++) {
        const int k0 = kt * 128;
        for (int i = 0; i < 4; i++) {
            const int ck = tid + i * 256;
            const int rk = ck >> 3, sk = (ck & 7) ^ (rk & 7);
            gld16(Kp + (size_t)(k0 + rk) * DIM + sk * 8, &Klds[ck * 8]);
            const int cv = tid + i * 256;
            const int dv = cv >> 4, pv = cv & 15;
            const int sv = (pv & 8) | ((pv ^ (dv & 7)) & 7);
            gld16(Vp + (size_t)dv * SEQ + k0 + sv * 8, &Vt[cv * 8]);
        }
        __syncthreads();

        // read the wave's K slice fully into registers FIRST (slice dies after)
        short8 ka[2][2];
        for (int kr = 0; kr < 2; kr++) {
            const int row = w * 32 + kr * 16 + l16;
            ka[kr][0] = *(const short8*)&Klds[row * 64 + ((quad ^ (l16 & 7)) * 8)];
            ka[kr][1] = *(const short8*)&Klds[row * 64 + (((4 + quad) ^ (l16 & 7)) * 8)];
        }

        float4v st[2][4];
        for (int kr = 0; kr < 2; kr++)
            for (int qc = 0; qc < 4; qc++) {
                float4v t = __builtin_amdgcn_mfma_f32_16x16x32_bf16(ka[kr][0], qb[qc][0], vz, 0, 0, 0);
                st[kr][qc] = __builtin_amdgcn_mfma_f32_16x16x32_bf16(ka[kr][1], qb[qc][1], t, 0, 0, 0);
            }

        // p = exp2(st); partial l; pack -> P in the wave's own Klds slice
        for (int kr = 0; kr < 2; kr++)
            for (int qc = 0; qc < 4; qc++) {
                float p0 = EXP2(st[kr][qc][0]), p1 = EXP2(st[kr][qc][1]);
                float p2 = EXP2(st[kr][qc][2]), p3 = EXP2(st[kr][qc][3]);
                lp[qc] += (p0 + p1) + (p2 + p3);
                u32x2 pk; pk[0] = pk2bf(p0, p1); pk[1] = pk2bf(p2, p3);
                *(u32x2*)((u32*)pw + (qc * 16 + l16) * 16 + kr * 8 + quad * 2) = pk;
            }
        asm volatile("" ::: "memory");    // same-wave DS order: P write < P read

        short8 pa[4], vb[4];
        for (int qc = 0; qc < 4; qc++)
            pa[qc] = *(const short8*)&pw[(qc * 16 + l16) * 32 + quad * 8];
        for (int nb = 0; nb < 4; nb++) {
            const int gk = w * 4 + quad;
            const int pos = (gk & 8) | ((gk ^ (l16 & 7)) & 7);
            vb[nb] = *(const short8*)&Vt[(nb * 16 + l16) * 128 + pos * 8];
        }
        for (int qc = 0; qc < 4; qc++)
            for (int nb = 0; nb < 4; nb++)
                acc[qc][nb] = __builtin_amdgcn_mfma_f32_16x16x32_bf16(pa[qc], vb[nb], acc[qc][nb], 0, 0, 0);
        __syncthreads();                  // all P reads done before next staging
    }

    // l reduction: quads, then per-wave partials to LDS
    for (int qc = 0; qc < 4; qc++) {
        lp[qc] += __shfl_xor(lp[qc], 16);
        lp[qc] += __shfl_xor(lp[qc], 32);
    }
    if (quad == 0)
        for (int qc = 0; qc < 4; qc++) Llds[w][qc * 16 + l16] = lp[qc];

    // partial-O reduction through dead K/V LDS
    if (w == 0 || w == 2) {
        float* buf = (w == 0) ? bufA : bufB;
        for (int qc = 0; qc < 4; qc++)
            for (int nb = 0; nb < 4; nb++)
                for (int r = 0; r < 4; r++)
                    buf[(qc * 16 + quad * 4 + r) * 64 + nb * 16 + l16] = acc[qc][nb][r];
    }
    __syncthreads();
    if (w == 1 || w == 3) {
        float* buf = (w == 1) ? bufA : bufB;
        for (int qc = 0; qc < 4; qc++)
            for (int nb = 0; nb < 4; nb++)
                for (int r = 0; r < 4; r++)
                    buf[(qc * 16 + quad * 4 + r) * 64 + nb * 16 + l16] += acc[qc][nb][r];
    }
    __syncthreads();

    {
        const int q = tid >> 2, dg = (tid & 3) * 16;
        const float l = Llds[0][q] + Llds[1][q] + Llds[2][q] + Llds[3][q];
        const float inv = 1.0f / l;
        short8 o0, o1;
        for (int e = 0; e < 8; e++) {
            o0[e] = (short)f2bf((bufA[q * 64 + dg + e] + bufB[q * 64 + dg + e]) * inv);
            o1[e] = (short)f2bf((bufA[q * 64 + dg + 8 + e] + bufB[q * 64 + dg + 8 + e]) * inv);
        }
        u16* dp = Op + (size_t)(q0 + q) * DIM + dg;
        *(short8*)(dp) = o0;
        *(short8*)(dp + 8) = o1;
    }
}

// ---------------------------------------------------------------------------
extern "C" void kernel_launch(void* const* d_in, const int* in_sizes, int n_in,
                              void* d_out, int out_size, void* d_ws, size_t ws_size,
                              hipStream_t stream)
{
    const float* q   = (const float*)d_in[0];
    const float* k   = (const float*)d_in[1];
    const float* v   = (const float*)d_in[2];
    const float* w_q = (const float*)d_in[3];
    const float* w_k = (const float*)d_in[4];
    const float* w_v = (const float*)d_in[5];
    const float* w_o = (const float*)d_in[6];
    float* out = (float*)d_out;

    u16* Abf  = (u16*)d_ws;            // 3*NE  bf16 copies of q,k,v
    u16* Wt   = Abf + 3 * NE;          // 4*WN  [w_o, w_q, w_k, w_v] transposed bf16
    u16* QKVb = Wt + 4 * WN;           // 3*NE: Q(pre-scaled),K natural; V [bh][d][s]
    u16* Cb   = Abf;                   // attn output aliases Abf

    dim3 blk(256);
    prep<<<dim3(7168), blk, 0, stream>>>(q, k, v, w_q, w_k, w_v, w_o, Abf, Wt);
    gemm_qkv<<<dim3(32, 8, 3), blk, 0, stream>>>(Abf, Wt, QKVb);
    attn_kernel<<<dim3(32, 32), blk, 0, stream>>>(QKVb, QKVb + NE, QKVb + 2 * NE, Cb);
    gemm_out<<<dim3(64, 8), blk, 0, stream>>>(Cb, Wt, out);
}

// Round 8
// 233.033 us; speedup vs baseline: 1.4680x; 1.4680x over previous
//
#include <hip/hip_runtime.h>
#include <hip/hip_bf16.h>

typedef unsigned short u16;
typedef unsigned int u32;
typedef short short8 __attribute__((ext_vector_type(8)));
typedef float float4v __attribute__((ext_vector_type(4)));
typedef u32 u32x2 __attribute__((ext_vector_type(2)));

#define SEQ 2048
#define DIM 1024
#define NHEAD 16
#define MROWS 4096                       // B*S
#define NE ((size_t)MROWS * DIM)         // 4M elements
#define WN ((size_t)DIM * DIM)           // 1M elements

#if __has_builtin(__builtin_amdgcn_exp2f)
#define EXP2(x) __builtin_amdgcn_exp2f(x)
#else
#define EXP2(x) exp2f(x)
#endif

__device__ inline u16 f2bf(float f) {
    union { float f; unsigned u; } v; v.f = f;
    unsigned r = v.u + 0x7fffu + ((v.u >> 16) & 1u);   // RNE
    return (u16)(r >> 16);
}
__device__ inline float bf2f(u16 s) {
    union { unsigned u; float f; } v; v.u = ((unsigned)s) << 16;
    return v.f;
}
__device__ inline u32 pk2bf(float a, float b) {       // packed RNE bf16x2
    union { __hip_bfloat162 h; u32 u; } cv;
    cv.h = __float22bfloat162_rn(float2{a, b});
    return cv.u;
}
// async global->LDS, 16B per lane; LDS dest = wave-uniform base + lane*16
__device__ inline void gld16(const void* g, void* l) {
    __builtin_amdgcn_global_load_lds(
        (const __attribute__((address_space(1))) void*)g,
        (__attribute__((address_space(3))) void*)l, 16, 0, 0);
}

// ---------------------------------------------------------------------------
// Prep (fused): blocks 0..6143 convert q,k,v fp32->bf16; blocks 6144..7167
// transpose W fp32[k][n] -> bf16 Wt[n][k] (z: 0=w_o,1=w_q,2=w_k,3=w_v).
// ---------------------------------------------------------------------------
__global__ __launch_bounds__(256) void prep(
    const float* __restrict__ q, const float* __restrict__ k,
    const float* __restrict__ v, const float* __restrict__ w_q,
    const float* __restrict__ w_k, const float* __restrict__ w_v,
    const float* __restrict__ w_o, u16* __restrict__ Abf, u16* __restrict__ Wt)
{
    __shared__ u16 T[64 * 66];
    const int bx = blockIdx.x;
    const int tid = threadIdx.x;

    if (bx < 6144) {
        const int z = bx >> 11, xb = bx & 2047;
        const float* s = (z == 0) ? q : (z == 1) ? k : v;
        const size_t i = ((size_t)xb * 256 + tid) * 8;
        float4v a = *(const float4v*)(s + i);
        float4v b = *(const float4v*)(s + i + 4);
        short8 o;
        for (int e = 0; e < 4; e++) { o[e] = (short)f2bf(a[e]); o[4 + e] = (short)f2bf(b[e]); }
        *(short8*)(Abf + (size_t)z * NE + i) = o;
        return;
    }

    const int t = bx - 6144;
    const int z = t & 3, tile = t >> 2;
    const float* src = (z == 0) ? w_o : (z == 1) ? w_q : (z == 2) ? w_k : w_v;
    const int kt = (tile >> 4) * 64, nt = (tile & 15) * 64;
    {
        const int row = tid >> 2, cg = (tid & 3) * 16;
        const float* sp = src + (size_t)(kt + row) * DIM + nt + cg;
        for (int i4 = 0; i4 < 4; i4++) {
            float4v f = *(const float4v*)(sp + i4 * 4);
            for (int e = 0; e < 4; e++)
                T[row * 66 + cg + i4 * 4 + e] = f2bf(f[e]);
        }
    }
    __syncthreads();
    {
        const int nr = tid >> 2, kg = (tid & 3) * 16;
        u16* dp = Wt + (size_t)z * WN + (size_t)(nt + nr) * DIM + kt + kg;
        short8 o0, o1;
        for (int e = 0; e < 8; e++) {
            o0[e] = (short)T[(kg + e) * 66 + nr];
            o1[e] = (short)T[(kg + 8 + e) * 66 + nr];
        }
        *(short8*)(dp) = o0;
        *(short8*)(dp + 8) = o1;
    }
}

// ---------------------------------------------------------------------------
// GEMM qkv: C = A[4096,1024] @ Wt[N,K]^T, 128x128 tile, BK=64, grid (32,8,3).
// z==0 (Q) scales output by 0.125*log2e (folded attention scale).
// z==2 (V) writes output transposed to [bh][d][s] via LDS.
// ---------------------------------------------------------------------------
__global__ __launch_bounds__(256) void gemm_qkv(
    const u16* __restrict__ Abf, const u16* __restrict__ Wtg, u16* __restrict__ QKVb)
{
    __shared__ u16 SMEM[2 * 128 * 64];   // 32 KB: Alds | Wlds ; epilogue-T alias
    u16* Alds = SMEM;
    u16* Wlds = SMEM + 128 * 64;

    const int z = blockIdx.z;
    const u16* A = Abf + (size_t)z * NE;
    const u16* W = Wtg + (size_t)(z + 1) * WN;

    const int tid = threadIdx.x;
    const int lane = tid & 63, w = tid >> 6;
    const int quad = lane >> 4, l16 = lane & 15;
    const int wr = w >> 1, wc = w & 1;
    const int m0 = blockIdx.x * 128, n0 = blockIdx.y * 128;

    float4v acc[4][4];
    float4v vz = {0.f, 0.f, 0.f, 0.f};
    for (int i = 0; i < 4; i++)
        for (int j = 0; j < 4; j++) acc[i][j] = vz;

    for (int k0 = 0; k0 < DIM; k0 += 64) {
        for (int i = 0; i < 4; i++) {
            const int c = tid + i * 256;                   // 1024 chunks each
            const int row = c >> 3, scc = (c & 7) ^ (row & 7);
            gld16(A + (size_t)(m0 + row) * DIM + k0 + scc * 8, &Alds[c * 8]);
            gld16(W + (size_t)(n0 + row) * DIM + k0 + scc * 8, &Wlds[c * 8]);
        }
        __syncthreads();

        for (int s = 0; s < 2; s++) {
            short8 a[4], b[4];
            for (int i = 0; i < 4; i++) {
                const int row = wr * 64 + i * 16 + l16;
                a[i] = *(const short8*)&Alds[row * 64 + (((s * 4 + quad) ^ (row & 7)) * 8)];
            }
            for (int j = 0; j < 4; j++) {
                const int row = wc * 64 + j * 16 + l16;
                b[j] = *(const short8*)&Wlds[row * 64 + (((s * 4 + quad) ^ (row & 7)) * 8)];
            }
            for (int i = 0; i < 4; i++)
                for (int j = 0; j < 4; j++)
                    acc[i][j] = __builtin_amdgcn_mfma_f32_16x16x32_bf16(a[i], b[j], acc[i][j], 0, 0, 0);
        }
        __syncthreads();
    }

    if (z < 2) {                          // Q (pre-scaled), K: natural layout
        const float sc = (z == 0) ? 0.125f * 1.44269504088896f : 1.0f;
        for (int i = 0; i < 4; i++) {
            int row = m0 + wr * 64 + i * 16 + quad * 4;
            for (int j = 0; j < 4; j++) {
                int col = n0 + wc * 64 + j * 16 + l16;
                for (int r = 0; r < 4; r++)
                    QKVb[(size_t)z * NE + (size_t)(row + r) * DIM + col] = f2bf(acc[i][j][r] * sc);
            }
        }
        return;
    }

    // z==2: V -> [bh][d][s] via LDS transpose (chunk-swizzled rows of 128 s)
    u16* T = SMEM;                        // [128 d][128 s], 32 KB
    for (int i = 0; i < 4; i++)
        for (int j = 0; j < 4; j++) {
            const int d = wc * 64 + j * 16 + l16;
            for (int r = 0; r < 4; r++) {
                const int s = wr * 64 + i * 16 + quad * 4 + r;
                T[d * 128 + (((s >> 3) ^ (d & 7)) * 8) + (s & 7)] = f2bf(acc[i][j][r]);
            }
        }
    __syncthreads();
    {
        u16* Vt = QKVb + 2 * NE;
        const int b = m0 >> 11, s_loc = m0 & 2047, h0 = n0 >> 6;
        const int c = lane & 15;                      // s-chunk
        for (int p = 0; p < 8; p++) {
            const int d = w * 32 + (lane >> 4) * 8 + p;
            short8 val = *(const short8*)&T[d * 128 + ((c ^ (d & 7)) * 8)];
            u16* dp = Vt + ((size_t)(b * 16 + h0 + (d >> 6)) * 64 + (d & 63)) * SEQ + s_loc + c * 8;
            *(short8*)dp = val;
        }
    }
}

// ---------------------------------------------------------------------------
// GEMM out: out[4096,1024] fp32 = Cb @ Wt[w_o]^T. 64x128 tile, BK=64,
// grid (64, 8) = 512 blocks (2/CU). Wave tile 32x64 (2x4 frags).
// ---------------------------------------------------------------------------
__global__ __launch_bounds__(256) void gemm_out(
    const u16* __restrict__ Cb, const u16* __restrict__ Wtg, float* __restrict__ out)
{
    __shared__ u16 Alds[64 * 64];        // 8 KB
    __shared__ u16 Wlds[128 * 64];       // 16 KB
    const u16* W = Wtg;                  // w_o at z=0

    const int tid = threadIdx.x;
    const int lane = tid & 63, w = tid >> 6;
    const int quad = lane >> 4, l16 = lane & 15;
    const int wr = w >> 1, wc = w & 1;
    const int m0 = blockIdx.x * 64, n0 = blockIdx.y * 128;

    float4v acc[2][4];
    float4v vz = {0.f, 0.f, 0.f, 0.f};
    for (int i = 0; i < 2; i++)
        for (int j = 0; j < 4; j++) acc[i][j] = vz;

    for (int k0 = 0; k0 < DIM; k0 += 64) {
        for (int i = 0; i < 2; i++) {
            const int c = tid + i * 256;
            const int row = c >> 3, scc = (c & 7) ^ (row & 7);
            gld16(Cb + (size_t)(m0 + row) * DIM + k0 + scc * 8, &Alds[c * 8]);
        }
        for (int i = 0; i < 4; i++) {
            const int c = tid + i * 256;
            const int row = c >> 3, scc = (c & 7) ^ (row & 7);
            gld16(W + (size_t)(n0 + row) * DIM + k0 + scc * 8, &Wlds[c * 8]);
        }
        __syncthreads();

        for (int s = 0; s < 2; s++) {
            short8 a[2], b[4];
            for (int i = 0; i < 2; i++) {
                const int row = wr * 32 + i * 16 + l16;
                a[i] = *(const short8*)&Alds[row * 64 + (((s * 4 + quad) ^ (row & 7)) * 8)];
            }
            for (int j = 0; j < 4; j++) {
                const int row = wc * 64 + j * 16 + l16;
                b[j] = *(const short8*)&Wlds[row * 64 + (((s * 4 + quad) ^ (row & 7)) * 8)];
            }
            for (int i = 0; i < 2; i++)
                for (int j = 0; j < 4; j++)
                    acc[i][j] = __builtin_amdgcn_mfma_f32_16x16x32_bf16(a[i], b[j], acc[i][j], 0, 0, 0);
        }
        __syncthreads();
    }

    for (int i = 0; i < 2; i++) {
        int row = m0 + wr * 32 + i * 16 + quad * 4;
        for (int j = 0; j < 4; j++) {
            int col = n0 + wc * 64 + j * 16 + l16;
            for (int r = 0; r < 4; r++)
                out[(size_t)(row + r) * DIM + col] = acc[i][j][r];
        }
    }
}

// ---------------------------------------------------------------------------
// Attention v5: q-tile 32 (register-halved so (256,4) fits WITHOUT spilling),
// k-tile 128 split-k over 4 waves (32 k each).  P aliased into the wave's own
// dead 4 KB Klds slice at stride 40 u16 (80 B) -> balanced pa reads.
// LDS = 33 KB -> 4 blocks/CU.  Q arrives pre-scaled by 0.125*log2e.
// Grid (32 bh, 64 qt) x 256.
// ---------------------------------------------------------------------------
__global__ __launch_bounds__(256, 4) void attn_kernel(
    const u16* __restrict__ Q, const u16* __restrict__ K,
    const u16* __restrict__ Vtg, u16* __restrict__ O)
{
    __shared__ u16 Klds[128 * 64];       // 16KB [k][d] swizzled; wave P alias
    __shared__ u16 Vt[64 * 128];         // 16KB [d][k] swizzled
    __shared__ float Llds[4][32];        // 512B
    float* bufA = (float*)Klds;          // epilogue: 32x64 fp32 = 8KB
    float* bufB = (float*)Vt;

    const int bh = blockIdx.x;
    const int q0 = blockIdx.y * 32;
    const int tid = threadIdx.x;
    const int lane = tid & 63, w = tid >> 6;
    const int quad = lane >> 4, l16 = lane & 15;

    const size_t base = (size_t)(bh >> 4) * SEQ * DIM + (bh & 15) * 64;
    const u16* Qp = Q + base;
    const u16* Kp = K + base;
    u16* Op = O + base;
    const u16* Vp = Vtg + (size_t)bh * 64 * SEQ;   // [d][s]

    // Q B-frags (pre-scaled): 2 q-subtiles x 2 d-halves
    short8 qb[2][2];
    for (int qc = 0; qc < 2; qc++)
        for (int s = 0; s < 2; s++)
            qb[qc][s] = *(const short8*)(Qp + (size_t)(q0 + qc * 16 + l16) * DIM + s * 32 + quad * 8);

    float4v acc[2][4];
    float4v vz = {0.f, 0.f, 0.f, 0.f};
    for (int qc = 0; qc < 2; qc++)
        for (int nb = 0; nb < 4; nb++) acc[qc][nb] = vz;
    float lp[2] = {0.f, 0.f};

    u16* pw = Klds + w * 32 * 64;        // wave's 4 KB slice: K rows, then P

    for (int kt = 0; kt < SEQ / 128; kt++) {
        const int k0 = kt * 128;
        for (int i = 0; i < 4; i++) {
            const int ck = tid + i * 256;
            const int rk = ck >> 3, sk = (ck & 7) ^ (rk & 7);
            gld16(Kp + (size_t)(k0 + rk) * DIM + sk * 8, &Klds[ck * 8]);
            const int cv = tid + i * 256;
            const int dv = cv >> 4, pv = cv & 15;
            const int sv = (pv & 8) | ((pv ^ (dv & 7)) & 7);
            gld16(Vp + (size_t)dv * SEQ + k0 + sv * 8, &Vt[cv * 8]);
        }
        __syncthreads();

        // read the wave's K slice into registers (slice dies after)
        short8 ka[2][2];
        for (int kr = 0; kr < 2; kr++) {
            const int row = w * 32 + kr * 16 + l16;
            ka[kr][0] = *(const short8*)&Klds[row * 64 + ((quad ^ (l16 & 7)) * 8)];
            ka[kr][1] = *(const short8*)&Klds[row * 64 + (((4 + quad) ^ (l16 & 7)) * 8)];
        }

        float4v st[2][2];
        for (int kr = 0; kr < 2; kr++)
            for (int qc = 0; qc < 2; qc++) {
                float4v t = __builtin_amdgcn_mfma_f32_16x16x32_bf16(ka[kr][0], qb[qc][0], vz, 0, 0, 0);
                st[kr][qc] = __builtin_amdgcn_mfma_f32_16x16x32_bf16(ka[kr][1], qb[qc][1], t, 0, 0, 0);
            }

        // p = exp2(st); partial l; pack -> P in wave slice, row stride 40 u16
        for (int kr = 0; kr < 2; kr++)
            for (int qc = 0; qc < 2; qc++) {
                float p0 = EXP2(st[kr][qc][0]), p1 = EXP2(st[kr][qc][1]);
                float p2 = EXP2(st[kr][qc][2]), p3 = EXP2(st[kr][qc][3]);
                lp[qc] += (p0 + p1) + (p2 + p3);
                u32x2 pk; pk[0] = pk2bf(p0, p1); pk[1] = pk2bf(p2, p3);
                *(u32x2*)((u32*)pw + (qc * 16 + l16) * 20 + kr * 8 + quad * 2) = pk;
            }
        asm volatile("" ::: "memory");    // same-wave DS order: P write < P read

        short8 pa[2], vb[4];
        for (int qc = 0; qc < 2; qc++)
            pa[qc] = *(const short8*)&pw[(qc * 16 + l16) * 40 + quad * 8];
        for (int nb = 0; nb < 4; nb++) {
            const int gk = w * 4 + quad;
            const int pos = (gk & 8) | ((gk ^ (l16 & 7)) & 7);
            vb[nb] = *(const short8*)&Vt[(nb * 16 + l16) * 128 + pos * 8];
        }
        for (int qc = 0; qc < 2; qc++)
            for (int nb = 0; nb < 4; nb++)
                acc[qc][nb] = __builtin_amdgcn_mfma_f32_16x16x32_bf16(pa[qc], vb[nb], acc[qc][nb], 0, 0, 0);
        __syncthreads();                  // all P/V reads done before next stage
    }

    // l reduction: quads, then per-wave partials to LDS
    for (int qc = 0; qc < 2; qc++) {
        lp[qc] += __shfl_xor(lp[qc], 16);
        lp[qc] += __shfl_xor(lp[qc], 32);
    }
    if (quad == 0)
        for (int qc = 0; qc < 2; qc++) Llds[w][qc * 16 + l16] = lp[qc];

    // partial-O reduction through dead K/V LDS (bufA = w0+w1, bufB = w2+w3)
    if (w == 0 || w == 2) {
        float* buf = (w == 0) ? bufA : bufB;
        for (int qc = 0; qc < 2; qc++)
            for (int nb = 0; nb < 4; nb++)
                for (int r = 0; r < 4; r++)
                    buf[(qc * 16 + quad * 4 + r) * 64 + nb * 16 + l16] = acc[qc][nb][r];
    }
    __syncthreads();
    if (w == 1 || w == 3) {
        float* buf = (w == 1) ? bufA : bufB;
        for (int qc = 0; qc < 2; qc++)
            for (int nb = 0; nb < 4; nb++)
                for (int r = 0; r < 4; r++)
                    buf[(qc * 16 + quad * 4 + r) * 64 + nb * 16 + l16] += acc[qc][nb][r];
    }
    __syncthreads();

    {   // combine: thread -> q = tid>>3 (0..31), 8 d-elements
        const int q = tid >> 3, dg = (tid & 7) * 8;
        const float l = Llds[0][q] + Llds[1][q] + Llds[2][q] + Llds[3][q];
        const float inv = 1.0f / l;
        short8 o;
        for (int e = 0; e < 8; e++)
            o[e] = (short)f2bf((bufA[q * 64 + dg + e] + bufB[q * 64 + dg + e]) * inv);
        *(short8*)(Op + (size_t)(q0 + q) * DIM + dg) = o;
    }
}

// ---------------------------------------------------------------------------
extern "C" void kernel_launch(void* const* d_in, const int* in_sizes, int n_in,
                              void* d_out, int out_size, void* d_ws, size_t ws_size,
                              hipStream_t stream)
{
    const float* q   = (const float*)d_in[0];
    const float* k   = (const float*)d_in[1];
    const float* v   = (const float*)d_in[2];
    const float* w_q = (const float*)d_in[3];
    const float* w_k = (const float*)d_in[4];
    const float* w_v = (const float*)d_in[5];
    const float* w_o = (const float*)d_in[6];
    float* out = (float*)d_out;

    u16* Abf  = (u16*)d_ws;            // 3*NE  bf16 copies of q,k,v
    u16* Wt   = Abf + 3 * NE;          // 4*WN  [w_o, w_q, w_k, w_v] transposed bf16
    u16* QKVb = Wt + 4 * WN;           // 3*NE: Q(pre-scaled),K natural; V [bh][d][s]
    u16* Cb   = Abf;                   // attn output aliases Abf

    dim3 blk(256);
    prep<<<dim3(7168), blk, 0, stream>>>(q, k, v, w_q, w_k, w_v, w_o, Abf, Wt);
    gemm_qkv<<<dim3(32, 8, 3), blk, 0, stream>>>(Abf, Wt, QKVb);
    attn_kernel<<<dim3(32, 64), blk, 0, stream>>>(QKVb, QKVb + NE, QKVb + 2 * NE, Cb);
    gemm_out<<<dim3(64, 8), blk, 0, stream>>>(Cb, Wt, out);
}